// Round 6
// baseline (330.134 us; speedup 1.0000x reference)
//
#include <hip/hip_runtime.h>
#include <hip/hip_bf16.h>

// GraphSAGE 2-layer forward.
// R6 changes vs R5:
//  1) Gathers restructured into dim-slab passes (32 dims = 3.2MB table slab
//     fits per-XCD 4MB L2). Slab-major layouts for p1/r1/h/p2/r2; slab-major
//     block ordering for temporal separation; 4 lanes/node (64B line per
//     edge-row-slab).
//  2) All streaming traffic (csr, r-tables, h/out stores) nontemporal so the
//     resident gather slab is not evicted.
//  3) Layer-2 GEMM A-reads consume slab-major h natively (kstep == slab).

#define THREADS 256

typedef __bf16 bf16x8 __attribute__((ext_vector_type(8)));
typedef float floatx4 __attribute__((ext_vector_type(4)));
typedef float f32x4 __attribute__((ext_vector_type(4)));
typedef unsigned int u32x4 __attribute__((ext_vector_type(4)));

union ABfrag { bf16x8 v; unsigned short u[8]; uint4 q; };

static __device__ __forceinline__ unsigned short f2bf(float f) {
    unsigned int u = __float_as_uint(f);
    u = (u + 0x7fffu + ((u >> 16) & 1u)) >> 16;   // round-to-nearest-even
    return (unsigned short)u;
}

static __device__ __forceinline__ void acc8(float* acc, uint4 v) {
    acc[0] += __uint_as_float(v.x << 16);
    acc[1] += __uint_as_float(v.x & 0xffff0000u);
    acc[2] += __uint_as_float(v.y << 16);
    acc[3] += __uint_as_float(v.y & 0xffff0000u);
    acc[4] += __uint_as_float(v.z << 16);
    acc[5] += __uint_as_float(v.z & 0xffff0000u);
    acc[6] += __uint_as_float(v.w << 16);
    acc[7] += __uint_as_float(v.w & 0xffff0000u);
}

// ---------------------------------------------------------------------------
// Cast four weight matrices to bf16: [Wl1 16384 | Wr1 16384 | Wl2 8192 | Wr2 8192]
__global__ __launch_bounds__(THREADS)
void cast_w(const float* __restrict__ a, const float* __restrict__ b,
            const float* __restrict__ c, const float* __restrict__ d,
            unsigned short* __restrict__ o) {
    int i = blockIdx.x * THREADS + threadIdx.x;
    if (i >= 49152) return;
    float v;
    if (i < 16384) v = a[i];
    else if (i < 32768) v = b[i - 16384];
    else if (i < 40960) v = c[i - 32768];
    else v = d[i - 40960];
    o[i] = f2bf(v);
}

// ---------------------------------------------------------------------------
// Coarse bucket (dst>>8) histogram: LDS-privatized
__global__ __launch_bounds__(THREADS)
void bucket_hist(const int* __restrict__ dst, int* __restrict__ bhist,
                 int E, int NB) {
    __shared__ int lh[THREADS];
    if (threadIdx.x < NB) lh[threadIdx.x] = 0;
    __syncthreads();
    int stride = gridDim.x * THREADS;
    for (int e = blockIdx.x * THREADS + threadIdx.x; e < E; e += stride)
        atomicAdd(&lh[dst[e] >> 8], 1);
    __syncthreads();
    if (threadIdx.x < NB && lh[threadIdx.x])
        atomicAdd(&bhist[threadIdx.x], lh[threadIdx.x]);
}

__global__ __launch_bounds__(THREADS)
void bucket_scan(const int* __restrict__ bhist, int* __restrict__ bucket_base,
                 int* __restrict__ bucketFill, int* __restrict__ rowptr,
                 int NB, int N, int E) {
    __shared__ int s[THREADS];
    int v = (threadIdx.x < NB) ? bhist[threadIdx.x] : 0;
    s[threadIdx.x] = v;
    __syncthreads();
    for (int off = 1; off < THREADS; off <<= 1) {
        int t = (threadIdx.x >= off) ? s[threadIdx.x - off] : 0;
        __syncthreads();
        s[threadIdx.x] += t;
        __syncthreads();
    }
    int excl = (threadIdx.x == 0) ? 0 : s[threadIdx.x - 1];
    if (threadIdx.x < NB) {
        bucket_base[threadIdx.x] = excl;
        bucketFill[threadIdx.x] = excl;
    }
    if (threadIdx.x == 0) {
        bucket_base[NB] = E;
        rowptr[N] = E;
    }
}

// Level-1 partition: block-exclusive reserved runs per 256-dst bucket.
__global__ __launch_bounds__(THREADS)
void bucket_part(const int* __restrict__ src, const int* __restrict__ dst,
                 int* __restrict__ bucketFill, unsigned int* __restrict__ pairs,
                 int E, int NB) {
    __shared__ int lh[THREADS];
    __shared__ int lbase[THREADS];
    __shared__ int lo[THREADS];
    int chunk = (E + gridDim.x - 1) / gridDim.x;
    int e0 = blockIdx.x * chunk;
    int e1 = min(E, e0 + chunk);
    if (threadIdx.x < NB) { lh[threadIdx.x] = 0; lo[threadIdx.x] = 0; }
    __syncthreads();
    for (int e = e0 + threadIdx.x; e < e1; e += THREADS)
        atomicAdd(&lh[dst[e] >> 8], 1);
    __syncthreads();
    if (threadIdx.x < NB)
        lbase[threadIdx.x] = lh[threadIdx.x] ? atomicAdd(&bucketFill[threadIdx.x], lh[threadIdx.x]) : 0;
    __syncthreads();
    for (int e = e0 + threadIdx.x; e < e1; e += THREADS) {
        int d = dst[e];
        int bk = d >> 8;
        int pos = lbase[bk] + atomicAdd(&lo[bk], 1);
        pairs[pos] = (unsigned int)src[e] | ((unsigned int)(d & 255) << 16);
    }
}

// Level-2: one block per bucket. LDS hist + scan -> rowptr, scatter ushort src.
__global__ __launch_bounds__(THREADS)
void bucket_sort(const unsigned int* __restrict__ pairs, const int* __restrict__ bucket_base,
                 int* __restrict__ rowptr, unsigned short* __restrict__ csr_src, int N) {
    __shared__ int lhist[THREADS];
    __shared__ int lscan[THREADS];
    __shared__ int loff[THREADS];
    int b = blockIdx.x;
    int s0 = bucket_base[b], s1 = bucket_base[b + 1];
    lhist[threadIdx.x] = 0;
    __syncthreads();
    for (int i = s0 + threadIdx.x; i < s1; i += THREADS)
        atomicAdd(&lhist[(pairs[i] >> 16) & 255], 1);
    __syncthreads();
    int v = lhist[threadIdx.x];
    lscan[threadIdx.x] = v;
    __syncthreads();
    for (int off = 1; off < THREADS; off <<= 1) {
        int t = (threadIdx.x >= off) ? lscan[threadIdx.x - off] : 0;
        __syncthreads();
        lscan[threadIdx.x] += t;
        __syncthreads();
    }
    int base = s0 + lscan[threadIdx.x] - v;
    int id = (b << 8) + threadIdx.x;
    if (id < N) rowptr[id] = base;
    loff[threadIdx.x] = base;
    __syncthreads();
    for (int i = s0 + threadIdx.x; i < s1; i += THREADS) {
        unsigned int pr = pairs[i];
        int pos = atomicAdd(&loff[(pr >> 16) & 255], 1);
        csr_src[pos] = (unsigned short)(pr & 0xffffu);
    }
}

// ---------------------------------------------------------------------------
// MFMA bf16 GEMM: one wave per 16-row M-tile, K=128, B-frags VGPR-resident.
// Output SLAB-MAJOR: [col>>5][row][col&31] (32-dim slabs).
// ASLAB: A is bf16 slab-major [ks][row][32] (kstep == slab). Else A fp32 [row][128].
template<int NOUT, bool A32, bool OBF, bool ASLAB>
__global__ __launch_bounds__(THREADS)
void gemm_mfma(const void* __restrict__ Ap, const unsigned short* __restrict__ Wb,
               const float* __restrict__ bias, void* __restrict__ outp, int M) {
    constexpr int CT = NOUT / 16;
    const int wv = threadIdx.x >> 6, ln = threadIdx.x & 63;
    const int bl = ln & 15, quad = ln >> 4;
    const int mt = blockIdx.x * 4 + wv;
    const size_t M32 = (size_t)M * 32;

    ABfrag Bf[CT][4];
    #pragma unroll
    for (int ct = 0; ct < CT; ++ct)
        #pragma unroll
        for (int ks = 0; ks < 4; ++ks)
            Bf[ct][ks].q = *(const uint4*)&Wb[(size_t)(ct * 16 + bl) * 128 + ks * 32 + quad * 8];

    if (mt * 16 >= M) return;
    const int m0 = mt * 16;
    const int arow = m0 + bl;

    floatx4 acc[CT];
    #pragma unroll
    for (int ct = 0; ct < CT; ++ct) acc[ct] = (floatx4){0.f, 0.f, 0.f, 0.f};

    #pragma unroll
    for (int ks = 0; ks < 4; ++ks) {
        ABfrag Af;
        if (A32) {
            const float* A = (const float*)Ap;
            const float4* p4 = (const float4*)&A[(size_t)arow * 128 + ks * 32 + quad * 8];
            float4 u0 = p4[0], u1 = p4[1];
            Af.u[0] = f2bf(u0.x); Af.u[1] = f2bf(u0.y);
            Af.u[2] = f2bf(u0.z); Af.u[3] = f2bf(u0.w);
            Af.u[4] = f2bf(u1.x); Af.u[5] = f2bf(u1.y);
            Af.u[6] = f2bf(u1.z); Af.u[7] = f2bf(u1.w);
        } else if (ASLAB) {
            Af.q = *(const uint4*)&((const unsigned short*)Ap)[(size_t)ks * M32 + (size_t)arow * 32 + quad * 8];
        } else {
            Af.q = *(const uint4*)&((const unsigned short*)Ap)[(size_t)arow * 128 + ks * 32 + quad * 8];
        }
        #pragma unroll
        for (int ct = 0; ct < CT; ++ct)
            acc[ct] = __builtin_amdgcn_mfma_f32_16x16x32_bf16(Af.v, Bf[ct][ks].v, acc[ct], 0, 0, 0);
    }

    #pragma unroll
    for (int ct = 0; ct < CT; ++ct) {
        int col = ct * 16 + bl;
        int slab = col >> 5, wi = col & 31;
        float bv = bias ? bias[col] : 0.f;
        size_t sbase = (size_t)slab * M32;
        #pragma unroll
        for (int i = 0; i < 4; ++i) {
            int row = m0 + quad * 4 + i;
            float v = acc[ct][i] + bv;
            if (OBF) ((unsigned short*)outp)[sbase + (size_t)row * 32 + wi] = f2bf(v);
            else     ((float*)outp)[sbase + (size_t)row * 32 + wi] = v;
        }
    }
}

// ---------------------------------------------------------------------------
// Slabbed gather layer 1: for slab s (4 slabs x 32 dims):
//   h[s][g][:] = relu( mean_{src} p1[s][src][:] + r1[s][g][:] )  (bf16 out)
// 4 lanes/node, 8 bf16/lane; slab table 3.2MB -> per-XCD L2 resident.
// csr/r1 loads and h stores nontemporal.
__global__ __launch_bounds__(THREADS)
void gather_h(const unsigned short* __restrict__ p1, const int* __restrict__ rowptr,
              const unsigned short* __restrict__ csr, const float* __restrict__ r1,
              unsigned short* __restrict__ h, int N, int nodeBlocks) {
    const size_t N32 = (size_t)N * 32;
    int slab = blockIdx.x / nodeBlocks;
    int nb = blockIdx.x - slab * nodeBlocks;
    int g = nb * 64 + (threadIdx.x >> 2);
    if (g >= N) return;
    int lane = threadIdx.x & 3;
    const unsigned short* ps = p1 + slab * N32;
    int start = rowptr[g], end = rowptr[g + 1];
    float acc[8] = {0.f, 0.f, 0.f, 0.f, 0.f, 0.f, 0.f, 0.f};
    int base = start;
    for (; base + 8 <= end; base += 8) {
        int sv0 = (int)__builtin_nontemporal_load(csr + base + lane);
        int sv1 = (int)__builtin_nontemporal_load(csr + base + 4 + lane);
        #pragma unroll
        for (int j = 0; j < 8; ++j) {
            int s = __shfl(j < 4 ? sv0 : sv1, j & 3, 4);
            acc8(acc, *(const uint4*)&ps[(size_t)s * 32 + lane * 8]);
        }
    }
    for (; base + 4 <= end; base += 4) {
        int sv = (int)__builtin_nontemporal_load(csr + base + lane);
        #pragma unroll
        for (int j = 0; j < 4; ++j) {
            int s = __shfl(sv, j, 4);
            acc8(acc, *(const uint4*)&ps[(size_t)s * 32 + lane * 8]);
        }
    }
    if (base < end) {
        int my = base + lane;
        int sv = (my < end) ? (int)csr[my] : 0;
        int m = end - base;
        for (int j = 0; j < m; ++j) {
            int s = __shfl(sv, j, 4);
            acc8(acc, *(const uint4*)&ps[(size_t)s * 32 + lane * 8]);
        }
    }
    float rc = 1.0f / fmaxf((float)(end - start), 1.0f);
    const f32x4* r4 = (const f32x4*)(r1 + slab * N32 + (size_t)g * 32 + lane * 8);
    f32x4 a = __builtin_nontemporal_load(r4);
    f32x4 b = __builtin_nontemporal_load(r4 + 1);
    float o[8];
    #pragma unroll
    for (int i = 0; i < 4; ++i) o[i] = fmaxf(acc[i] * rc + a[i], 0.f);
    #pragma unroll
    for (int i = 0; i < 4; ++i) o[4 + i] = fmaxf(acc[4 + i] * rc + b[i], 0.f);
    u32x4 u;
    u[0] = (unsigned)f2bf(o[0]) | ((unsigned)f2bf(o[1]) << 16);
    u[1] = (unsigned)f2bf(o[2]) | ((unsigned)f2bf(o[3]) << 16);
    u[2] = (unsigned)f2bf(o[4]) | ((unsigned)f2bf(o[5]) << 16);
    u[3] = (unsigned)f2bf(o[6]) | ((unsigned)f2bf(o[7]) << 16);
    __builtin_nontemporal_store(u, (u32x4*)(h + slab * N32 + (size_t)g * 32 + lane * 8));
}

// Slabbed gather layer 2 (final): out[g][s*32+d] = mean p2[s][src][d] + r2[s][g][d]
__global__ __launch_bounds__(THREADS)
void gather_out(const unsigned short* __restrict__ p2, const int* __restrict__ rowptr,
                const unsigned short* __restrict__ csr, const float* __restrict__ r2,
                float* __restrict__ out, int N, int nodeBlocks) {
    const size_t N32 = (size_t)N * 32;
    int slab = blockIdx.x / nodeBlocks;
    int nb = blockIdx.x - slab * nodeBlocks;
    int g = nb * 64 + (threadIdx.x >> 2);
    if (g >= N) return;
    int lane = threadIdx.x & 3;
    const unsigned short* ps = p2 + slab * N32;
    int start = rowptr[g], end = rowptr[g + 1];
    float acc[8] = {0.f, 0.f, 0.f, 0.f, 0.f, 0.f, 0.f, 0.f};
    int base = start;
    for (; base + 8 <= end; base += 8) {
        int sv0 = (int)__builtin_nontemporal_load(csr + base + lane);
        int sv1 = (int)__builtin_nontemporal_load(csr + base + 4 + lane);
        #pragma unroll
        for (int j = 0; j < 8; ++j) {
            int s = __shfl(j < 4 ? sv0 : sv1, j & 3, 4);
            acc8(acc, *(const uint4*)&ps[(size_t)s * 32 + lane * 8]);
        }
    }
    for (; base + 4 <= end; base += 4) {
        int sv = (int)__builtin_nontemporal_load(csr + base + lane);
        #pragma unroll
        for (int j = 0; j < 4; ++j) {
            int s = __shfl(sv, j, 4);
            acc8(acc, *(const uint4*)&ps[(size_t)s * 32 + lane * 8]);
        }
    }
    if (base < end) {
        int my = base + lane;
        int sv = (my < end) ? (int)csr[my] : 0;
        int m = end - base;
        for (int j = 0; j < m; ++j) {
            int s = __shfl(sv, j, 4);
            acc8(acc, *(const uint4*)&ps[(size_t)s * 32 + lane * 8]);
        }
    }
    float rc = 1.0f / fmaxf((float)(end - start), 1.0f);
    const f32x4* r4 = (const f32x4*)(r2 + slab * N32 + (size_t)g * 32 + lane * 8);
    f32x4 a = __builtin_nontemporal_load(r4);
    f32x4 b = __builtin_nontemporal_load(r4 + 1);
    f32x4 o0, o1;
    #pragma unroll
    for (int i = 0; i < 4; ++i) o0[i] = acc[i] * rc + a[i];
    #pragma unroll
    for (int i = 0; i < 4; ++i) o1[i] = acc[4 + i] * rc + b[i];
    f32x4* o4 = (f32x4*)(out + (size_t)g * 64 + slab * 32 + lane * 8);
    __builtin_nontemporal_store(o0, o4);
    __builtin_nontemporal_store(o1, o4 + 1);
}

// ---------------------------------------------------------------------------
extern "C" void kernel_launch(void* const* d_in, const int* in_sizes, int n_in,
                              void* d_out, int out_size, void* d_ws, size_t ws_size,
                              hipStream_t stream) {
    const float* x   = (const float*)d_in[0];
    const int* edges = (const int*)d_in[1];
    const float* Wl1 = (const float*)d_in[2];
    const float* Wr1 = (const float*)d_in[3];
    const float* b1  = (const float*)d_in[4];
    const float* Wl2 = (const float*)d_in[5];
    const float* Wr2 = (const float*)d_in[6];
    const float* b2  = (const float*)d_in[7];
    float* out = (float*)d_out;

    const int N = in_sizes[0] / 128;     // 50000 (< 65536)
    const int E = in_sizes[1] / 2;       // 1600000
    const int NB = (N + 255) >> 8;       // 196
    const int* src = edges;
    const int* dstv = edges + E;

    // Workspace layout (slab-major tables: [slab][node][32])
    char* wsp = (char*)d_ws;
    unsigned short* p1  = (unsigned short*)wsp;  wsp += (size_t)N * 128 * 2;   // 12.8 MB
    float* r1           = (float*)wsp;           wsp += (size_t)N * 128 * 4;   // 25.6 MB
    unsigned short* h   = (unsigned short*)wsp;  wsp += (size_t)N * 128 * 2;   // 12.8 MB
    unsigned short* p2  = (unsigned short*)wsp;  wsp += (size_t)N * 64 * 2;    //  6.4 MB
    float* r2           = (float*)wsp;           wsp += (size_t)N * 64 * 4;    // 12.8 MB
    unsigned int* pairs = (unsigned int*)wsp;    wsp += (size_t)E * 4;         //  6.4 MB
    unsigned short* csr = (unsigned short*)wsp;  wsp += (size_t)E * 2;         //  3.2 MB
    unsigned short* Wb  = (unsigned short*)wsp;  wsp += (size_t)49152 * 2;     // 96 KB
    int* rowptr         = (int*)wsp;             wsp += (size_t)(N + 1) * 4;
    int* bhist          = (int*)wsp;             wsp += (size_t)NB * 4;
    int* bucket_base    = (int*)wsp;             wsp += (size_t)(NB + 1) * 4;
    int* bucketFill     = (int*)wsp;             wsp += (size_t)NB * 4;

    unsigned short* Wl1b = Wb;
    unsigned short* Wr1b = Wb + 16384;
    unsigned short* Wl2b = Wb + 32768;
    unsigned short* Wr2b = Wb + 40960;

    hipMemsetAsync(bhist, 0, (size_t)NB * sizeof(int), stream);

    // --- weight cast + CSR build ---
    cast_w<<<192, THREADS, 0, stream>>>(Wl1, Wr1, Wl2, Wr2, Wb);
    bucket_hist<<<400, THREADS, 0, stream>>>(dstv, bhist, E, NB);
    bucket_scan<<<1, THREADS, 0, stream>>>(bhist, bucket_base, bucketFill, rowptr, NB, N, E);
    bucket_part<<<512, THREADS, 0, stream>>>(src, dstv, bucketFill, pairs, E, NB);
    bucket_sort<<<NB, THREADS, 0, stream>>>(pairs, bucket_base, rowptr, csr, N);

    const int MT = (N + 15) / 16;                 // 3125
    const int gemmBlocks = (MT + 3) / 4;          // 782
    const int nodeBlocks = (N + 63) / 64;         // 782

    // --- layer 1 ---
    gemm_mfma<128, true, true,  false><<<gemmBlocks, THREADS, 0, stream>>>(x, Wl1b, nullptr, p1, N);
    gemm_mfma<128, true, false, false><<<gemmBlocks, THREADS, 0, stream>>>(x, Wr1b, b1, r1, N);
    gather_h<<<4 * nodeBlocks, THREADS, 0, stream>>>(p1, rowptr, csr, r1, h, N, nodeBlocks);

    // --- layer 2 ---
    gemm_mfma<64, false, true,  true><<<gemmBlocks, THREADS, 0, stream>>>(h, Wl2b, nullptr, p2, N);
    gemm_mfma<64, false, false, true><<<gemmBlocks, THREADS, 0, stream>>>(h, Wr2b, b2, r2, N);
    gather_out<<<2 * nodeBlocks, THREADS, 0, stream>>>(p2, rowptr, csr, r2, out, N, nodeBlocks);
}

// Round 7
// 295.841 us; speedup vs baseline: 1.1159x; 1.1159x over previous
//
#include <hip/hip_runtime.h>
#include <hip/hip_bf16.h>

// GraphSAGE 2-layer forward.
// R7 changes vs R6:
//  1) CSR build -> 4-phase fully-coalesced pipeline (part1 local LDS sort +
//     coalesced pairs, part2/3 scans, part4 per-bucket LDS assemble+sort),
//     zero global atomics, no memset.
//  2) GEMMs: 2 dispatches (both outputs per layer via grid.y), 64-col jobs
//     (CT=4 -> ~100 VGPR, 2x occupancy); x pre-cast to bf16 (fused w/ cast_w).
//  3) Gathers unchanged: measured at per-CU vmem pipe ceiling (~6.8 TB/s
//     aggregate effective > 6.3 TB/s streaming ceiling).

#define THREADS 256
#define NBLK1 512          // csr_part1 grid (chunk = E/512 = 3125)
#define BCAP 12288         // part4 LDS pair capacity (bucket avg 8163, sigma~90)

typedef __bf16 bf16x8 __attribute__((ext_vector_type(8)));
typedef float floatx4 __attribute__((ext_vector_type(4)));
typedef float f32x4 __attribute__((ext_vector_type(4)));
typedef unsigned int u32x4 __attribute__((ext_vector_type(4)));

union ABfrag { bf16x8 v; unsigned short u[8]; uint4 q; };

static __device__ __forceinline__ unsigned short f2bf(float f) {
    unsigned int u = __float_as_uint(f);
    u = (u + 0x7fffu + ((u >> 16) & 1u)) >> 16;   // round-to-nearest-even
    return (unsigned short)u;
}

static __device__ __forceinline__ void acc8(float* acc, uint4 v) {
    acc[0] += __uint_as_float(v.x << 16);
    acc[1] += __uint_as_float(v.x & 0xffff0000u);
    acc[2] += __uint_as_float(v.y << 16);
    acc[3] += __uint_as_float(v.y & 0xffff0000u);
    acc[4] += __uint_as_float(v.z << 16);
    acc[5] += __uint_as_float(v.z & 0xffff0000u);
    acc[6] += __uint_as_float(v.w << 16);
    acc[7] += __uint_as_float(v.w & 0xffff0000u);
}

// ---------------------------------------------------------------------------
// Cast x (float4-vectorized) and the 4 weight matrices to bf16.
__global__ __launch_bounds__(THREADS)
void cast_xw(const float* __restrict__ x, const float* __restrict__ a,
             const float* __restrict__ b, const float* __restrict__ c,
             const float* __restrict__ d, unsigned short* __restrict__ xb,
             unsigned short* __restrict__ Wb, int nx4) {
    int i = blockIdx.x * THREADS + threadIdx.x;
    if (i < nx4) {
        float4 v = ((const float4*)x)[i];
        ushort4 u;
        u.x = f2bf(v.x); u.y = f2bf(v.y); u.z = f2bf(v.z); u.w = f2bf(v.w);
        ((ushort4*)xb)[i] = u;
        return;
    }
    int j = i - nx4;
    if (j >= 49152) return;
    float v;
    if (j < 16384) v = a[j];
    else if (j < 32768) v = b[j - 16384];
    else if (j < 40960) v = c[j - 32768];
    else v = d[j - 40960];
    Wb[j] = f2bf(v);
}

// ---------------------------------------------------------------------------
// CSR phase 1: each of 512 blocks locally sorts its edge chunk by 256-dst
// bucket (LDS hist+scan+scatter), streams pairs out COALESCED (same global
// offsets), writes packed (localBase<<16 | count) per bucket.
__global__ __launch_bounds__(THREADS)
void csr_part1(const int* __restrict__ src, const int* __restrict__ dst,
               unsigned int* __restrict__ pairs, unsigned int* __restrict__ counts,
               int E, int chunk, int NB) {
    __shared__ int lh[THREADS], lsc[THREADS], lpos[THREADS];
    __shared__ unsigned int stage[3328];
    int e0 = blockIdx.x * chunk, e1 = min(E, e0 + chunk);
    int t = threadIdx.x;
    lh[t] = 0;
    __syncthreads();
    for (int e = e0 + t; e < e1; e += THREADS) atomicAdd(&lh[dst[e] >> 8], 1);
    __syncthreads();
    int v = lh[t];
    lsc[t] = v;
    __syncthreads();
    for (int off = 1; off < THREADS; off <<= 1) {
        int tv = (t >= off) ? lsc[t - off] : 0;
        __syncthreads();
        lsc[t] += tv;
        __syncthreads();
    }
    int base = lsc[t] - v;
    lpos[t] = base;
    __syncthreads();
    for (int e = e0 + t; e < e1; e += THREADS) {
        int dd = dst[e];
        int p = atomicAdd(&lpos[dd >> 8], 1);
        stage[p] = (unsigned int)src[e] | ((unsigned int)(dd & 255) << 16);
    }
    __syncthreads();
    int n = e1 - e0;
    for (int i = t; i < n; i += THREADS) pairs[e0 + i] = stage[i];
    if (t < NB) counts[(size_t)blockIdx.x * 256 + t] = ((unsigned int)base << 16) | (unsigned int)v;
}

// CSR phase 2: one block per bucket scans its 512 per-block counts ->
// relative bases bbase[bucket][blk] + bucket total.
__global__ __launch_bounds__(THREADS)
void csr_part2(const unsigned int* __restrict__ counts, int* __restrict__ bbase,
               int* __restrict__ totals) {
    __shared__ int s[THREADS];
    int b = blockIdx.x, t = threadIdx.x;
    int c0 = (int)(counts[(size_t)t * 256 + b] & 0xffffu);
    int c1 = (int)(counts[(size_t)(t + 256) * 256 + b] & 0xffffu);
    s[t] = c0;
    __syncthreads();
    for (int off = 1; off < THREADS; off <<= 1) {
        int tv = (t >= off) ? s[t - off] : 0;
        __syncthreads();
        s[t] += tv;
        __syncthreads();
    }
    int e0 = s[t] - c0;
    int S0 = s[THREADS - 1];
    __syncthreads();
    s[t] = c1;
    __syncthreads();
    for (int off = 1; off < THREADS; off <<= 1) {
        int tv = (t >= off) ? s[t - off] : 0;
        __syncthreads();
        s[t] += tv;
        __syncthreads();
    }
    int e1 = S0 + s[t] - c1;
    int T = S0 + s[THREADS - 1];
    bbase[(size_t)b * NBLK1 + t] = e0;
    bbase[(size_t)b * NBLK1 + 256 + t] = e1;
    if (t == 0) totals[b] = T;
}

// CSR phase 3: single-block scan of bucket totals -> bucket_base; rowptr[N]=E.
__global__ __launch_bounds__(THREADS)
void csr_part3(const int* __restrict__ totals, int* __restrict__ bucket_base,
               int* __restrict__ rowptr, int NB, int N, int E) {
    __shared__ int s[THREADS];
    int t = threadIdx.x;
    int v = (t < NB) ? totals[t] : 0;
    s[t] = v;
    __syncthreads();
    for (int off = 1; off < THREADS; off <<= 1) {
        int tv = (t >= off) ? s[t - off] : 0;
        __syncthreads();
        s[t] += tv;
        __syncthreads();
    }
    if (t < NB) bucket_base[t] = s[t] - v;
    if (t == 0) rowptr[N] = E;
}

// CSR phase 4: one block per bucket. Assemble bucket pairs in LDS from the
// 512 block runs (8 threads/run), hist+scan 256 dsts -> rowptr, LDS sort,
// stream csr out coalesced.
__global__ __launch_bounds__(THREADS)
void csr_part4(const unsigned int* __restrict__ pairs, const unsigned int* __restrict__ counts,
               const int* __restrict__ bbase, const int* __restrict__ bucket_base,
               const int* __restrict__ totals, int* __restrict__ rowptr,
               unsigned short* __restrict__ csr, int N, int chunk) {
    __shared__ unsigned int bp[BCAP];
    __shared__ unsigned short sp[BCAP];
    __shared__ int lhist[THREADS], lscan[THREADS], loff[THREADS];
    int b = blockIdx.x, t = threadIdx.x;
    int rid = t >> 3, j0 = t & 7;
    for (int blk = rid; blk < NBLK1; blk += 32) {
        unsigned int pc = counts[(size_t)blk * 256 + b];
        int len = (int)(pc & 0xffffu);
        int lb = (int)(pc >> 16);
        int ss = blk * chunk + lb;
        int dd = bbase[(size_t)b * NBLK1 + blk];
        for (int j = j0; j < len; j += 8) bp[dd + j] = pairs[ss + j];
    }
    lhist[t] = 0;
    __syncthreads();
    int sz = totals[b];
    for (int i = t; i < sz; i += THREADS) atomicAdd(&lhist[(bp[i] >> 16) & 255], 1);
    __syncthreads();
    int v = lhist[t];
    lscan[t] = v;
    __syncthreads();
    for (int off = 1; off < THREADS; off <<= 1) {
        int tv = (t >= off) ? lscan[t - off] : 0;
        __syncthreads();
        lscan[t] += tv;
        __syncthreads();
    }
    int rel = lscan[t] - v;
    int gb = bucket_base[b];
    int id = (b << 8) + t;
    if (id < N) rowptr[id] = gb + rel;
    loff[t] = rel;
    __syncthreads();
    for (int i = t; i < sz; i += THREADS) {
        unsigned int p = bp[i];
        int pos = atomicAdd(&loff[(p >> 16) & 255], 1);
        sp[pos] = (unsigned short)(p & 0xffffu);
    }
    __syncthreads();
    for (int i = t; i < sz; i += THREADS) csr[gb + i] = sp[i];
}

// ---------------------------------------------------------------------------
// MFMA bf16 GEMM, both outputs of a layer in one dispatch.
// grid.y: NOUT=128 -> 4 jobs (outSel=y>>1 [0:p,1:r], chalf=y&1);
//         NOUT=64  -> 2 jobs (outSel=y). 64 cols per job (CT=4).
// A: bf16; ASLAB -> slab-major [ks][row][32], else row-major [row][128].
// Outputs slab-major: p bf16, r fp32 (+bias).
template<int NOUT, bool ASLAB>
__global__ __launch_bounds__(THREADS)
void gemm_mfma(const unsigned short* __restrict__ A, const unsigned short* __restrict__ W0,
               const unsigned short* __restrict__ W1, const float* __restrict__ biasR,
               unsigned short* __restrict__ pOut, float* __restrict__ rOut, int M) {
    constexpr int CT = 4;
    int job = blockIdx.y;
    int outSel, chalf;
    if (NOUT == 128) { outSel = job >> 1; chalf = job & 1; }
    else             { outSel = job;      chalf = 0; }
    const unsigned short* W = (outSel ? W1 : W0) + chalf * 64 * 128;

    const int wv = threadIdx.x >> 6, ln = threadIdx.x & 63;
    const int bl = ln & 15, quad = ln >> 4;
    const int mt = blockIdx.x * 4 + wv;
    const size_t M32 = (size_t)M * 32;

    ABfrag Bf[CT][4];
    #pragma unroll
    for (int ct = 0; ct < CT; ++ct)
        #pragma unroll
        for (int ks = 0; ks < 4; ++ks)
            Bf[ct][ks].q = *(const uint4*)&W[(size_t)(ct * 16 + bl) * 128 + ks * 32 + quad * 8];

    if (mt * 16 >= M) return;
    const int m0 = mt * 16;
    const int arow = m0 + bl;

    floatx4 acc[CT];
    #pragma unroll
    for (int ct = 0; ct < CT; ++ct) acc[ct] = (floatx4){0.f, 0.f, 0.f, 0.f};

    #pragma unroll
    for (int ks = 0; ks < 4; ++ks) {
        ABfrag Af;
        if (ASLAB) Af.q = *(const uint4*)&A[(size_t)ks * M32 + (size_t)arow * 32 + quad * 8];
        else       Af.q = *(const uint4*)&A[(size_t)arow * 128 + ks * 32 + quad * 8];
        #pragma unroll
        for (int ct = 0; ct < CT; ++ct)
            acc[ct] = __builtin_amdgcn_mfma_f32_16x16x32_bf16(Af.v, Bf[ct][ks].v, acc[ct], 0, 0, 0);
    }

    #pragma unroll
    for (int ct = 0; ct < CT; ++ct) {
        int col = chalf * 64 + ct * 16 + bl;
        int slab = col >> 5, wi = col & 31;
        size_t sbase = (size_t)slab * M32;
        float bv = outSel ? biasR[col] : 0.f;
        #pragma unroll
        for (int i = 0; i < 4; ++i) {
            int row = m0 + quad * 4 + i;
            float val = acc[ct][i] + bv;
            if (outSel == 0) pOut[sbase + (size_t)row * 32 + wi] = f2bf(val);
            else             rOut[sbase + (size_t)row * 32 + wi] = val;
        }
    }
}

// ---------------------------------------------------------------------------
// Slabbed gather layer 1: h[s][g][:] = relu(mean p1[s][src][:] + r1[s][g][:]), bf16 out.
__global__ __launch_bounds__(THREADS)
void gather_h(const unsigned short* __restrict__ p1, const int* __restrict__ rowptr,
              const unsigned short* __restrict__ csr, const float* __restrict__ r1,
              unsigned short* __restrict__ h, int N, int nodeBlocks) {
    const size_t N32 = (size_t)N * 32;
    int slab = blockIdx.x / nodeBlocks;
    int nb = blockIdx.x - slab * nodeBlocks;
    int g = nb * 64 + (threadIdx.x >> 2);
    if (g >= N) return;
    int lane = threadIdx.x & 3;
    const unsigned short* ps = p1 + slab * N32;
    int start = rowptr[g], end = rowptr[g + 1];
    float acc[8] = {0.f, 0.f, 0.f, 0.f, 0.f, 0.f, 0.f, 0.f};
    int base = start;
    for (; base + 8 <= end; base += 8) {
        int sv0 = (int)__builtin_nontemporal_load(csr + base + lane);
        int sv1 = (int)__builtin_nontemporal_load(csr + base + 4 + lane);
        #pragma unroll
        for (int j = 0; j < 8; ++j) {
            int s = __shfl(j < 4 ? sv0 : sv1, j & 3, 4);
            acc8(acc, *(const uint4*)&ps[(size_t)s * 32 + lane * 8]);
        }
    }
    for (; base + 4 <= end; base += 4) {
        int sv = (int)__builtin_nontemporal_load(csr + base + lane);
        #pragma unroll
        for (int j = 0; j < 4; ++j) {
            int s = __shfl(sv, j, 4);
            acc8(acc, *(const uint4*)&ps[(size_t)s * 32 + lane * 8]);
        }
    }
    if (base < end) {
        int my = base + lane;
        int sv = (my < end) ? (int)csr[my] : 0;
        int m = end - base;
        for (int j = 0; j < m; ++j) {
            int s = __shfl(sv, j, 4);
            acc8(acc, *(const uint4*)&ps[(size_t)s * 32 + lane * 8]);
        }
    }
    float rc = 1.0f / fmaxf((float)(end - start), 1.0f);
    const f32x4* r4 = (const f32x4*)(r1 + slab * N32 + (size_t)g * 32 + lane * 8);
    f32x4 a = __builtin_nontemporal_load(r4);
    f32x4 b = __builtin_nontemporal_load(r4 + 1);
    float o[8];
    #pragma unroll
    for (int i = 0; i < 4; ++i) o[i] = fmaxf(acc[i] * rc + a[i], 0.f);
    #pragma unroll
    for (int i = 0; i < 4; ++i) o[4 + i] = fmaxf(acc[4 + i] * rc + b[i], 0.f);
    u32x4 u;
    u[0] = (unsigned)f2bf(o[0]) | ((unsigned)f2bf(o[1]) << 16);
    u[1] = (unsigned)f2bf(o[2]) | ((unsigned)f2bf(o[3]) << 16);
    u[2] = (unsigned)f2bf(o[4]) | ((unsigned)f2bf(o[5]) << 16);
    u[3] = (unsigned)f2bf(o[6]) | ((unsigned)f2bf(o[7]) << 16);
    __builtin_nontemporal_store(u, (u32x4*)(h + slab * N32 + (size_t)g * 32 + lane * 8));
}

// Slabbed gather layer 2 (final): out[g][s*32+d] = mean p2[s][src][d] + r2[s][g][d]
__global__ __launch_bounds__(THREADS)
void gather_out(const unsigned short* __restrict__ p2, const int* __restrict__ rowptr,
                const unsigned short* __restrict__ csr, const float* __restrict__ r2,
                float* __restrict__ out, int N, int nodeBlocks) {
    const size_t N32 = (size_t)N * 32;
    int slab = blockIdx.x / nodeBlocks;
    int nb = blockIdx.x - slab * nodeBlocks;
    int g = nb * 64 + (threadIdx.x >> 2);
    if (g >= N) return;
    int lane = threadIdx.x & 3;
    const unsigned short* ps = p2 + slab * N32;
    int start = rowptr[g], end = rowptr[g + 1];
    float acc[8] = {0.f, 0.f, 0.f, 0.f, 0.f, 0.f, 0.f, 0.f};
    int base = start;
    for (; base + 8 <= end; base += 8) {
        int sv0 = (int)__builtin_nontemporal_load(csr + base + lane);
        int sv1 = (int)__builtin_nontemporal_load(csr + base + 4 + lane);
        #pragma unroll
        for (int j = 0; j < 8; ++j) {
            int s = __shfl(j < 4 ? sv0 : sv1, j & 3, 4);
            acc8(acc, *(const uint4*)&ps[(size_t)s * 32 + lane * 8]);
        }
    }
    for (; base + 4 <= end; base += 4) {
        int sv = (int)__builtin_nontemporal_load(csr + base + lane);
        #pragma unroll
        for (int j = 0; j < 4; ++j) {
            int s = __shfl(sv, j, 4);
            acc8(acc, *(const uint4*)&ps[(size_t)s * 32 + lane * 8]);
        }
    }
    if (base < end) {
        int my = base + lane;
        int sv = (my < end) ? (int)csr[my] : 0;
        int m = end - base;
        for (int j = 0; j < m; ++j) {
            int s = __shfl(sv, j, 4);
            acc8(acc, *(const uint4*)&ps[(size_t)s * 32 + lane * 8]);
        }
    }
    float rc = 1.0f / fmaxf((float)(end - start), 1.0f);
    const f32x4* r4 = (const f32x4*)(r2 + slab * N32 + (size_t)g * 32 + lane * 8);
    f32x4 a = __builtin_nontemporal_load(r4);
    f32x4 b = __builtin_nontemporal_load(r4 + 1);
    f32x4 o0, o1;
    #pragma unroll
    for (int i = 0; i < 4; ++i) o0[i] = acc[i] * rc + a[i];
    #pragma unroll
    for (int i = 0; i < 4; ++i) o1[i] = acc[4 + i] * rc + b[i];
    f32x4* o4 = (f32x4*)(out + (size_t)g * 64 + slab * 32 + lane * 8);
    __builtin_nontemporal_store(o0, o4);
    __builtin_nontemporal_store(o1, o4 + 1);
}

// ---------------------------------------------------------------------------
extern "C" void kernel_launch(void* const* d_in, const int* in_sizes, int n_in,
                              void* d_out, int out_size, void* d_ws, size_t ws_size,
                              hipStream_t stream) {
    const float* x   = (const float*)d_in[0];
    const int* edges = (const int*)d_in[1];
    const float* Wl1 = (const float*)d_in[2];
    const float* Wr1 = (const float*)d_in[3];
    const float* b1  = (const float*)d_in[4];
    const float* Wl2 = (const float*)d_in[5];
    const float* Wr2 = (const float*)d_in[6];
    const float* b2  = (const float*)d_in[7];
    float* out = (float*)d_out;

    const int N = in_sizes[0] / 128;     // 50000 (< 65536)
    const int E = in_sizes[1] / 2;       // 1600000
    const int NB = (N + 255) >> 8;       // 196
    const int chunk = (E + NBLK1 - 1) / NBLK1;   // 3125 (<= 3328 stage cap)
    const int* src = edges;
    const int* dstv = edges + E;

    // Workspace layout (slab-major tables [slab][node][32])
    char* wsp = (char*)d_ws;
    unsigned short* p1  = (unsigned short*)wsp;  wsp += (size_t)N * 128 * 2;   // 12.8 MB
    float* r1           = (float*)wsp;           wsp += (size_t)N * 128 * 4;   // 25.6 MB
    unsigned short* h   = (unsigned short*)wsp;  wsp += (size_t)N * 128 * 2;   // 12.8 MB
    unsigned short* p2  = (unsigned short*)wsp;  wsp += (size_t)N * 64 * 2;    //  6.4 MB
    float* r2           = (float*)wsp;           wsp += (size_t)N * 64 * 4;    // 12.8 MB
    unsigned short* xb  = (unsigned short*)wsp;  wsp += (size_t)N * 128 * 2;   // 12.8 MB
    unsigned int* pairs = (unsigned int*)wsp;    wsp += (size_t)E * 4;         //  6.4 MB
    unsigned short* csr = (unsigned short*)wsp;  wsp += (size_t)E * 2;         //  3.2 MB
    unsigned short* Wb  = (unsigned short*)wsp;  wsp += (size_t)49152 * 2;     // 96 KB
    unsigned int* counts= (unsigned int*)wsp;    wsp += (size_t)NBLK1 * 256 * 4; // 512 KB
    int* bbase          = (int*)wsp;             wsp += (size_t)NB * NBLK1 * 4;  // 400 KB
    int* totals         = (int*)wsp;             wsp += (size_t)NB * 4;
    int* bucket_base    = (int*)wsp;             wsp += (size_t)NB * 4;
    int* rowptr         = (int*)wsp;             wsp += (size_t)(N + 1) * 4;

    unsigned short* Wl1b = Wb;
    unsigned short* Wr1b = Wb + 16384;
    unsigned short* Wl2b = Wb + 32768;
    unsigned short* Wr2b = Wb + 40960;

    const int nx4 = N * 128 / 4;                       // 1.6M float4 casts
    const int castBlocks = (nx4 + 49152 + THREADS - 1) / THREADS;

    // --- casts + CSR build (no atomics, no memset) ---
    cast_xw<<<castBlocks, THREADS, 0, stream>>>(x, Wl1, Wr1, Wl2, Wr2, xb, Wb, nx4);
    csr_part1<<<NBLK1, THREADS, 0, stream>>>(src, dstv, pairs, counts, E, chunk, NB);
    csr_part2<<<NB, THREADS, 0, stream>>>(counts, bbase, totals);
    csr_part3<<<1, THREADS, 0, stream>>>(totals, bucket_base, rowptr, NB, N, E);
    csr_part4<<<NB, THREADS, 0, stream>>>(pairs, counts, bbase, bucket_base, totals,
                                          rowptr, csr, N, chunk);

    const int MT = (N + 15) / 16;                 // 3125
    const int gemmBlocks = (MT + 3) / 4;          // 782
    const int nodeBlocks = (N + 63) / 64;         // 782

    // --- layer 1 ---
    gemm_mfma<128, false><<<dim3(gemmBlocks, 4), THREADS, 0, stream>>>(xb, Wl1b, Wr1b, b1, p1, r1, N);
    gather_h<<<4 * nodeBlocks, THREADS, 0, stream>>>(p1, rowptr, csr, r1, h, N, nodeBlocks);

    // --- layer 2 ---
    gemm_mfma<64, true><<<dim3(gemmBlocks, 2), THREADS, 0, stream>>>(h, Wl2b, Wr2b, b2, p2, r2, N);
    gather_out<<<2 * nodeBlocks, THREADS, 0, stream>>>(p2, rowptr, csr, r2, out, N, nodeBlocks);
}

// Round 9
// 288.991 us; speedup vs baseline: 1.1424x; 1.0237x over previous
//
#include <hip/hip_runtime.h>
#include <hip/hip_bf16.h>

// GraphSAGE 2-layer forward.
// R9 changes vs R8 (which failed absmax on fp8 tables):
//  1) Gather tables reverted to bf16 (fp8's 3-bit mantissa blew the error
//     budget: 0.213 vs 0.0284 threshold). Gather/GEMM kernels = proven R7
//     versions (slab-major natural order, no pi permutation).
//  2) KEPT R8's dispatch fusion: fused cast+CSR-part1; self-contained
//     csr_part4 (dead runbase scans stripped).
//  3) NEW: csr_part4 fused INTO the layer-1 GEMM dispatch (grid.y=5, y==0 ->
//     CSR finalize blocks, y>=1 -> GEMM job y-1): CSR finalize hides under
//     GEMM execution instead of serializing. 5 dispatches + 1 memset.

#define THREADS 256
#define NBLK1 512          // csr part1 grid (chunk = 3125 <= 3328 stage cap)
#define BCAP 12288         // part4 LDS capacity (bucket mean 8192, max ~8600)

typedef __bf16 bf16x8 __attribute__((ext_vector_type(8)));
typedef float floatx4 __attribute__((ext_vector_type(4)));
typedef float f32x4 __attribute__((ext_vector_type(4)));
typedef unsigned int u32x4 __attribute__((ext_vector_type(4)));

union ABfrag { bf16x8 v; unsigned short u[8]; uint4 q; };

static __device__ __forceinline__ unsigned short f2bf(float f) {
    unsigned int u = __float_as_uint(f);
    u = (u + 0x7fffu + ((u >> 16) & 1u)) >> 16;   // RNE
    return (unsigned short)u;
}

static __device__ __forceinline__ void acc8(float* acc, uint4 v) {
    acc[0] += __uint_as_float(v.x << 16);
    acc[1] += __uint_as_float(v.x & 0xffff0000u);
    acc[2] += __uint_as_float(v.y << 16);
    acc[3] += __uint_as_float(v.y & 0xffff0000u);
    acc[4] += __uint_as_float(v.z << 16);
    acc[5] += __uint_as_float(v.z & 0xffff0000u);
    acc[6] += __uint_as_float(v.w << 16);
    acc[7] += __uint_as_float(v.w & 0xffff0000u);
}

// ---------------------------------------------------------------------------
// D1: fused cast (x->bf16, W->bf16 natural order) + CSR part1 (local LDS
// bucket sort, coalesced pair output, per-bucket (base<<16|count) records,
// global totals via 196 atomics/block).
__global__ __launch_bounds__(THREADS)
void fused_cast_p1(const float* __restrict__ x, const float* __restrict__ wa,
                   const float* __restrict__ wb, const float* __restrict__ wc,
                   const float* __restrict__ wd, unsigned short* __restrict__ xb,
                   unsigned short* __restrict__ Wb, int nx4,
                   const int* __restrict__ src, const int* __restrict__ dst,
                   unsigned int* __restrict__ pairs, unsigned int* __restrict__ counts,
                   int* __restrict__ totals, int E, int chunk, int NB) {
    __shared__ int lh[THREADS], lsc[THREADS], lpos[THREADS];
    __shared__ unsigned int stage[3328];
    int t = threadIdx.x;
    if (blockIdx.x < NBLK1) {
        // ---- CSR part1 role ----
        int e0 = blockIdx.x * chunk, e1 = min(E, e0 + chunk);
        lh[t] = 0;
        __syncthreads();
        for (int e = e0 + t; e < e1; e += THREADS) atomicAdd(&lh[dst[e] >> 8], 1);
        __syncthreads();
        int v = lh[t];
        lsc[t] = v;
        __syncthreads();
        for (int off = 1; off < THREADS; off <<= 1) {
            int tv = (t >= off) ? lsc[t - off] : 0;
            __syncthreads();
            lsc[t] += tv;
            __syncthreads();
        }
        int base = lsc[t] - v;
        lpos[t] = base;
        __syncthreads();
        for (int e = e0 + t; e < e1; e += THREADS) {
            int dd = dst[e];
            int p = atomicAdd(&lpos[dd >> 8], 1);
            stage[p] = (unsigned int)src[e] | ((unsigned int)(dd & 255) << 16);
        }
        __syncthreads();
        int n = e1 - e0;
        for (int i = t; i < n; i += THREADS) pairs[e0 + i] = stage[i];
        if (t < NB) {
            counts[(size_t)blockIdx.x * 256 + t] = ((unsigned int)base << 16) | (unsigned int)v;
            if (v) atomicAdd(&totals[t], v);
        }
        return;
    }
    // ---- cast role ----
    int i = (blockIdx.x - NBLK1) * THREADS + t;
    if (i < nx4) {
        float4 v = ((const float4*)x)[i];
        ushort4 u;
        u.x = f2bf(v.x); u.y = f2bf(v.y); u.z = f2bf(v.z); u.w = f2bf(v.w);
        ((ushort4*)xb)[i] = u;
        return;
    }
    int j = i - nx4;
    if (j >= 49152) return;
    float v;
    if (j < 16384) v = wa[j];
    else if (j < 32768) v = wb[j - 16384];
    else if (j < 40960) v = wc[j - 32768];
    else v = wd[j - 40960];
    Wb[j] = f2bf(v);
}

// ---------------------------------------------------------------------------
// MFMA bf16 GEMM body (R7-proven). One wave per 16-row M-tile, K=128,
// B-frags VGPR-resident, 64 cols per job. Outputs slab-major [col>>5][row][32]:
// p bf16, r fp32 (+bias). NOUT=128: jobs 0,1 -> p halves; 2,3 -> r halves.
// NOUT=64: job 0 -> p, 1 -> r. ASLAB: A bf16 [ks][row][32], else [row][128].
template<int NOUT, bool ASLAB>
static __device__ __forceinline__
void gemm_body(const unsigned short* __restrict__ A, const unsigned short* __restrict__ W0,
               const unsigned short* __restrict__ W1, const float* __restrict__ biasR,
               unsigned short* __restrict__ pOut, float* __restrict__ rOut,
               int M, int job) {
    constexpr int CT = 4;
    int outSel, chalf;
    if (NOUT == 128) { outSel = job >> 1; chalf = job & 1; }
    else             { outSel = job;      chalf = 0; }
    const unsigned short* W = (outSel ? W1 : W0) + chalf * 64 * 128;

    const int wv = threadIdx.x >> 6, ln = threadIdx.x & 63;
    const int bl = ln & 15, quad = ln >> 4;
    const int mt = blockIdx.x * 4 + wv;
    const size_t M32 = (size_t)M * 32;

    ABfrag Bf[CT][4];
    #pragma unroll
    for (int ct = 0; ct < CT; ++ct)
        #pragma unroll
        for (int ks = 0; ks < 4; ++ks)
            Bf[ct][ks].q = *(const uint4*)&W[(size_t)(ct * 16 + bl) * 128 + ks * 32 + quad * 8];

    if (mt * 16 >= M) return;
    const int m0 = mt * 16;
    const int arow = m0 + bl;

    floatx4 acc[CT];
    #pragma unroll
    for (int ct = 0; ct < CT; ++ct) acc[ct] = (floatx4){0.f, 0.f, 0.f, 0.f};

    #pragma unroll
    for (int ks = 0; ks < 4; ++ks) {
        ABfrag Af;
        if (ASLAB) Af.q = *(const uint4*)&A[(size_t)ks * M32 + (size_t)arow * 32 + quad * 8];
        else       Af.q = *(const uint4*)&A[(size_t)arow * 128 + ks * 32 + quad * 8];
        #pragma unroll
        for (int ct = 0; ct < CT; ++ct)
            acc[ct] = __builtin_amdgcn_mfma_f32_16x16x32_bf16(Af.v, Bf[ct][ks].v, acc[ct], 0, 0, 0);
    }

    #pragma unroll
    for (int ct = 0; ct < CT; ++ct) {
        int col = chalf * 64 + ct * 16 + bl;
        int slab = col >> 5, wi = col & 31;
        size_t sbase = (size_t)slab * M32;
        float bv = outSel ? biasR[col] : 0.f;
        #pragma unroll
        for (int i = 0; i < 4; ++i) {
            int row = m0 + quad * 4 + i;
            float val = acc[ct][i] + bv;
            if (outSel == 0) pOut[sbase + (size_t)row * 32 + wi] = f2bf(val);
            else             rOut[sbase + (size_t)row * 32 + wi] = val;
        }
    }
}

// ---------------------------------------------------------------------------
// D2: fused layer-1 GEMM + CSR finalize.
// grid (gemmBlocks, 5): y==0 && x<NB -> per-bucket CSR finalize (scan totals
// -> bucket base, LDS hist+scan 256 dsts from L2-hot pairs, rowptr, LDS
// scatter, coalesced csr stream-out); y in [1,4] -> GEMM job y-1.
__global__ __launch_bounds__(THREADS)
void gemm128_csr(const unsigned short* __restrict__ A, const unsigned short* __restrict__ W0,
                 const unsigned short* __restrict__ W1, const float* __restrict__ biasR,
                 unsigned short* __restrict__ pOut, float* __restrict__ rOut, int M,
                 const unsigned int* __restrict__ pairs, const unsigned int* __restrict__ counts,
                 const int* __restrict__ totals, int* __restrict__ rowptr,
                 unsigned short* __restrict__ csr, int N, int E, int NB, int chunk) {
    __shared__ unsigned short sp[BCAP];
    __shared__ int s0arr[THREADS], lhist[THREADS], lscan[THREADS], loff[THREADS];
    __shared__ int gbs;

    if (blockIdx.y != 0) {
        gemm_body<128, false>(A, W0, W1, biasR, pOut, rOut, M, blockIdx.y - 1);
        return;
    }
    int b = blockIdx.x, t = threadIdx.x;
    if (b >= NB) return;

    // bucket_base[b] = exclusive prefix of totals
    int tv = (t < NB) ? totals[t] : 0;
    s0arr[t] = tv;
    __syncthreads();
    for (int off = 1; off < THREADS; off <<= 1) {
        int x = (t >= off) ? s0arr[t - off] : 0;
        __syncthreads();
        s0arr[t] += x;
        __syncthreads();
    }
    if (t == b) gbs = s0arr[t] - tv;
    int sz = totals[b];
    lhist[t] = 0;
    __syncthreads();

    // hist pass over the 512 per-block runs of bucket b (8 threads/run)
    int rid = t >> 3, j0 = t & 7;
    for (int blk = rid; blk < NBLK1; blk += 32) {
        unsigned int pc = counts[(size_t)blk * 256 + b];
        int len = (int)(pc & 0xffffu);
        const unsigned int* pp = pairs + (size_t)blk * chunk + (pc >> 16);
        for (int j = j0; j < len; j += 8) atomicAdd(&lhist[(pp[j] >> 16) & 255], 1);
    }
    __syncthreads();
    int v = lhist[t];
    lscan[t] = v;
    __syncthreads();
    for (int off = 1; off < THREADS; off <<= 1) {
        int x = (t >= off) ? lscan[t - off] : 0;
        __syncthreads();
        lscan[t] += x;
        __syncthreads();
    }
    int rel = lscan[t] - v;
    int gb = gbs;
    int id = (b << 8) + t;
    if (id < N) rowptr[id] = gb + rel;
    loff[t] = rel;
    __syncthreads();

    // scatter pass into LDS, then coalesced stream-out
    for (int blk = rid; blk < NBLK1; blk += 32) {
        unsigned int pc = counts[(size_t)blk * 256 + b];
        int len = (int)(pc & 0xffffu);
        const unsigned int* pp = pairs + (size_t)blk * chunk + (pc >> 16);
        for (int j = j0; j < len; j += 8) {
            unsigned int p = pp[j];
            int pos = atomicAdd(&loff[(p >> 16) & 255], 1);
            sp[pos] = (unsigned short)(p & 0xffffu);
        }
    }
    __syncthreads();
    for (int i = t; i < sz; i += THREADS) csr[gb + i] = sp[i];
    if (b == NB - 1 && t == 0) rowptr[N] = E;
}

// Layer-2 GEMM (standalone): grid.y = 2 jobs.
__global__ __launch_bounds__(THREADS)
void gemm64(const unsigned short* __restrict__ A, const unsigned short* __restrict__ W0,
            const unsigned short* __restrict__ W1, const float* __restrict__ biasR,
            unsigned short* __restrict__ pOut, float* __restrict__ rOut, int M) {
    gemm_body<64, true>(A, W0, W1, biasR, pOut, rOut, M, blockIdx.y);
}

// ---------------------------------------------------------------------------
// Slabbed gather layer 1 (R7-proven): h[s][g][:] = relu(mean p1[s][src][:]
// + r1[s][g][:]), bf16 out. 4 lanes/node, 8 bf16 (16B) per lane, 4 slabs.
__global__ __launch_bounds__(THREADS)
void gather_h(const unsigned short* __restrict__ p1, const int* __restrict__ rowptr,
              const unsigned short* __restrict__ csr, const float* __restrict__ r1,
              unsigned short* __restrict__ h, int N, int nodeBlocks) {
    const size_t N32 = (size_t)N * 32;
    int slab = blockIdx.x / nodeBlocks;
    int nb = blockIdx.x - slab * nodeBlocks;
    int g = nb * 64 + (threadIdx.x >> 2);
    if (g >= N) return;
    int lane = threadIdx.x & 3;
    const unsigned short* ps = p1 + slab * N32;
    int start = rowptr[g], end = rowptr[g + 1];
    float acc[8] = {0.f, 0.f, 0.f, 0.f, 0.f, 0.f, 0.f, 0.f};
    int base = start;
    for (; base + 8 <= end; base += 8) {
        int sv0 = (int)__builtin_nontemporal_load(csr + base + lane);
        int sv1 = (int)__builtin_nontemporal_load(csr + base + 4 + lane);
        #pragma unroll
        for (int j = 0; j < 8; ++j) {
            int s = __shfl(j < 4 ? sv0 : sv1, j & 3, 4);
            acc8(acc, *(const uint4*)&ps[(size_t)s * 32 + lane * 8]);
        }
    }
    for (; base + 4 <= end; base += 4) {
        int sv = (int)__builtin_nontemporal_load(csr + base + lane);
        #pragma unroll
        for (int j = 0; j < 4; ++j) {
            int s = __shfl(sv, j, 4);
            acc8(acc, *(const uint4*)&ps[(size_t)s * 32 + lane * 8]);
        }
    }
    if (base < end) {
        int my = base + lane;
        int sv = (my < end) ? (int)csr[my] : 0;
        int m = end - base;
        for (int j = 0; j < m; ++j) {
            int s = __shfl(sv, j, 4);
            acc8(acc, *(const uint4*)&ps[(size_t)s * 32 + lane * 8]);
        }
    }
    float rc = 1.0f / fmaxf((float)(end - start), 1.0f);
    const f32x4* r4 = (const f32x4*)(r1 + slab * N32 + (size_t)g * 32 + lane * 8);
    f32x4 a = __builtin_nontemporal_load(r4);
    f32x4 b = __builtin_nontemporal_load(r4 + 1);
    float o[8];
    #pragma unroll
    for (int i = 0; i < 4; ++i) o[i] = fmaxf(acc[i] * rc + a[i], 0.f);
    #pragma unroll
    for (int i = 0; i < 4; ++i) o[4 + i] = fmaxf(acc[4 + i] * rc + b[i], 0.f);
    u32x4 u;
    u[0] = (unsigned)f2bf(o[0]) | ((unsigned)f2bf(o[1]) << 16);
    u[1] = (unsigned)f2bf(o[2]) | ((unsigned)f2bf(o[3]) << 16);
    u[2] = (unsigned)f2bf(o[4]) | ((unsigned)f2bf(o[5]) << 16);
    u[3] = (unsigned)f2bf(o[6]) | ((unsigned)f2bf(o[7]) << 16);
    __builtin_nontemporal_store(u, (u32x4*)(h + slab * N32 + (size_t)g * 32 + lane * 8));
}

// Slabbed gather layer 2 (final, R7-proven): out[g][s*32+d] = mean p2[s][src][d]
// + r2[s][g][d], fp32 out.
__global__ __launch_bounds__(THREADS)
void gather_out(const unsigned short* __restrict__ p2, const int* __restrict__ rowptr,
                const unsigned short* __restrict__ csr, const float* __restrict__ r2,
                float* __restrict__ out, int N, int nodeBlocks) {
    const size_t N32 = (size_t)N * 32;
    int slab = blockIdx.x / nodeBlocks;
    int nb = blockIdx.x - slab * nodeBlocks;
    int g = nb * 64 + (threadIdx.x >> 2);
    if (g >= N) return;
    int lane = threadIdx.x & 3;
    const unsigned short* ps = p2 + slab * N32;
    int start = rowptr[g], end = rowptr[g + 1];
    float acc[8] = {0.f, 0.f, 0.f, 0.f, 0.f, 0.f, 0.f, 0.f};
    int base = start;
    for (; base + 8 <= end; base += 8) {
        int sv0 = (int)__builtin_nontemporal_load(csr + base + lane);
        int sv1 = (int)__builtin_nontemporal_load(csr + base + 4 + lane);
        #pragma unroll
        for (int j = 0; j < 8; ++j) {
            int s = __shfl(j < 4 ? sv0 : sv1, j & 3, 4);
            acc8(acc, *(const uint4*)&ps[(size_t)s * 32 + lane * 8]);
        }
    }
    for (; base + 4 <= end; base += 4) {
        int sv = (int)__builtin_nontemporal_load(csr + base + lane);
        #pragma unroll
        for (int j = 0; j < 4; ++j) {
            int s = __shfl(sv, j, 4);
            acc8(acc, *(const uint4*)&ps[(size_t)s * 32 + lane * 8]);
        }
    }
    if (base < end) {
        int my = base + lane;
        int sv = (my < end) ? (int)csr[my] : 0;
        int m = end - base;
        for (int j = 0; j < m; ++j) {
            int s = __shfl(sv, j, 4);
            acc8(acc, *(const uint4*)&ps[(size_t)s * 32 + lane * 8]);
        }
    }
    float rc = 1.0f / fmaxf((float)(end - start), 1.0f);
    const f32x4* r4 = (const f32x4*)(r2 + slab * N32 + (size_t)g * 32 + lane * 8);
    f32x4 a = __builtin_nontemporal_load(r4);
    f32x4 b = __builtin_nontemporal_load(r4 + 1);
    f32x4 o0, o1;
    #pragma unroll
    for (int i = 0; i < 4; ++i) o0[i] = acc[i] * rc + a[i];
    #pragma unroll
    for (int i = 0; i < 4; ++i) o1[i] = acc[4 + i] * rc + b[i];
    f32x4* o4 = (f32x4*)(out + (size_t)g * 64 + slab * 32 + lane * 8);
    __builtin_nontemporal_store(o0, o4);
    __builtin_nontemporal_store(o1, o4 + 1);
}

// ---------------------------------------------------------------------------
extern "C" void kernel_launch(void* const* d_in, const int* in_sizes, int n_in,
                              void* d_out, int out_size, void* d_ws, size_t ws_size,
                              hipStream_t stream) {
    const float* x   = (const float*)d_in[0];
    const int* edges = (const int*)d_in[1];
    const float* Wl1 = (const float*)d_in[2];
    const float* Wr1 = (const float*)d_in[3];
    const float* b1  = (const float*)d_in[4];
    const float* Wl2 = (const float*)d_in[5];
    const float* Wr2 = (const float*)d_in[6];
    const float* b2  = (const float*)d_in[7];
    float* out = (float*)d_out;

    const int N = in_sizes[0] / 128;     // 50000 (< 65536)
    const int E = in_sizes[1] / 2;       // 1600000
    const int NB = (N + 255) >> 8;       // 196
    const int chunk = (E + NBLK1 - 1) / NBLK1;   // 3125
    const int* src = edges;
    const int* dstv = edges + E;

    // Workspace layout (slab-major tables [slab][node][32])
    char* wsp = (char*)d_ws;
    unsigned short* p1  = (unsigned short*)wsp;  wsp += (size_t)N * 128 * 2;   // 12.8 MB bf16 [4][N][32]
    float* r1           = (float*)wsp;           wsp += (size_t)N * 128 * 4;   // 25.6 MB fp32 [4][N][32]
    unsigned short* h   = (unsigned short*)wsp;  wsp += (size_t)N * 128 * 2;   // 12.8 MB bf16 [4][N][32]
    unsigned short* p2  = (unsigned short*)wsp;  wsp += (size_t)N * 64 * 2;    //  6.4 MB bf16 [2][N][32]
    float* r2           = (float*)wsp;           wsp += (size_t)N * 64 * 4;    // 12.8 MB fp32 [2][N][32]
    unsigned short* xb  = (unsigned short*)wsp;  wsp += (size_t)N * 128 * 2;   // 12.8 MB bf16
    unsigned int* pairs = (unsigned int*)wsp;    wsp += (size_t)E * 4;         //  6.4 MB
    unsigned short* csr = (unsigned short*)wsp;  wsp += (size_t)E * 2;         //  3.2 MB
    unsigned short* Wb  = (unsigned short*)wsp;  wsp += (size_t)49152 * 2;     // 96 KB
    unsigned int* counts= (unsigned int*)wsp;    wsp += (size_t)NBLK1 * 256 * 4; // 512 KB
    int* totals         = (int*)wsp;             wsp += 256 * 4;
    int* rowptr         = (int*)wsp;             wsp += (size_t)(N + 1) * 4;

    unsigned short* Wl1b = Wb;
    unsigned short* Wr1b = Wb + 16384;
    unsigned short* Wl2b = Wb + 32768;
    unsigned short* Wr2b = Wb + 40960;

    const int nx4 = N * 128 / 4;
    const int castBlocks = (nx4 + 49152 + THREADS - 1) / THREADS;

    hipMemsetAsync(totals, 0, 256 * sizeof(int), stream);

    // D1: fused cast + CSR part1
    fused_cast_p1<<<NBLK1 + castBlocks, THREADS, 0, stream>>>(
        x, Wl1, Wr1, Wl2, Wr2, xb, Wb, nx4, src, dstv, pairs, counts, totals, E, chunk, NB);

    const int MT = (N + 15) / 16;                 // 3125
    const int gemmBlocks = (MT + 3) / 4;          // 782
    const int nodeBlocks = (N + 63) / 64;         // 782

    // D2: layer-1 GEMM (4 jobs) + CSR finalize fused (y==0)
    gemm128_csr<<<dim3(gemmBlocks, 5), THREADS, 0, stream>>>(
        xb, Wl1b, Wr1b, b1, p1, r1, N,
        pairs, counts, totals, rowptr, csr, N, E, NB, chunk);

    // D3: gather layer 1
    gather_h<<<4 * nodeBlocks, THREADS, 0, stream>>>(p1, rowptr, csr, r1, h, N, nodeBlocks);

    // D4: layer-2 GEMM
    gemm64<<<dim3(gemmBlocks, 2), THREADS, 0, stream>>>(h, Wl2b, Wr2b, b2, p2, r2, N);

    // D5: gather layer 2 -> final output
    gather_out<<<2 * nodeBlocks, THREADS, 0, stream>>>(p2, rowptr, csr, r2, out, N, nodeBlocks);
}